// Round 12
// baseline (105.318 us; speedup 1.0000x reference)
//
#include <hip/hip_runtime.h>
#include <math.h>

#define ALPHA 0.3f
#define KN 32

__device__ __forceinline__ float leaky_f(float x) { return x >= 0.f ? x : ALPHA * x; }

// ---------------------------------------------------------------------------
// K_A: 16 nodes/block, each wave owns 4 nodes CONCURRENTLY (batched GEMV):
//   h0[n,h] = leaky( sum_c emb[n,c]*Q0w[c,h] + Q0b[h] )
//   wcache[n,k] = wmat[n, nbr[n,k]]   (issued FIRST; latency hides under GEMV)
// sQ reads shared across the 4 nodes; sX broadcasts vectorize to b128.
// ---------------------------------------------------------------------------
__global__ __launch_bounds__(256) void k_dense_gather(
    const float* __restrict__ X,
    const float* __restrict__ Qw,
    const float* __restrict__ Qb,
    const float* __restrict__ wmat,
    const int*  __restrict__ nbr,
    float* __restrict__ wcache,      // may be null
    float* __restrict__ Hout,
    int N)
{
    __shared__ float sQ[64 * 64];    // 16 KB
    __shared__ float sX[4][4][64];   // 4 KB   [wid][j][c]
    const int tid  = threadIdx.x;
    const int wid  = tid >> 6;
    const int lane = tid & 63;
    const int bs   = blockIdx.x * 16;
    const int nbase = bs + wid * 4;

    // --- random gathers first: 512 (node,k) entries = 2 per thread ---
    int gid[2]; float gw[2];
    #pragma unroll
    for (int u = 0; u < 2; ++u) {
        int e = tid + u * 256;
        int n = bs + (e >> 5); if (n >= N) n = N - 1;
        gid[u] = nbr[(size_t)n * KN + (e & 31)];
    }
    #pragma unroll
    for (int u = 0; u < 2; ++u) {
        int e = tid + u * 256;
        int n = bs + (e >> 5); if (n >= N) n = N - 1;
        gw[u] = wmat[(size_t)n * (size_t)N + gid[u]];
    }

    // --- own 4 x-rows ---
    float xr[4];
    #pragma unroll
    for (int j = 0; j < 4; ++j) {
        int n = nbase + j; if (n >= N) n = N - 1;
        xr[j] = X[(size_t)n * 64 + lane];
    }

    // --- stage Q0 (float4, 4/thread) while gathers are in flight ---
    {
        const float4* s = (const float4*)Qw; float4* d = (float4*)sQ;
        #pragma unroll
        for (int i = 0; i < 4; ++i) d[i * 256 + tid] = s[i * 256 + tid];
    }
    #pragma unroll
    for (int j = 0; j < 4; ++j) sX[wid][j][lane] = xr[j];
    __syncthreads();

    // --- batched GEMV: 4 nodes share each sQ read ---
    const float qb = Qb[lane];
    float acc[4] = {qb, qb, qb, qb};
    const float4* sx4 = (const float4*)&sX[wid][0][0];   // [j*16 + c4]
    #pragma unroll
    for (int c4 = 0; c4 < 16; ++c4) {
        float4 xv[4];
        #pragma unroll
        for (int j = 0; j < 4; ++j) xv[j] = sx4[j * 16 + c4];
        #pragma unroll
        for (int u = 0; u < 4; ++u) {
            float qv = sQ[(c4 * 4 + u) * 64 + lane];
            #pragma unroll
            for (int j = 0; j < 4; ++j)
                acc[j] = fmaf((&xv[j].x)[u], qv, acc[j]);
        }
    }
    #pragma unroll
    for (int j = 0; j < 4; ++j) {
        int n = nbase + j;
        if (n < N) Hout[(size_t)n * 64 + lane] = leaky_f(acc[j]);
    }

    // --- persist gathered weights (coalesced) ---
    if (wcache) {
        #pragma unroll
        for (int u = 0; u < 2; ++u) {
            int e = tid + u * 256;
            if (bs + (e >> 5) < N) wcache[(size_t)bs * KN + e] = gw[u];
        }
    }
}

// ---------------------------------------------------------------------------
// K_B/K_C: conv layer, 16 nodes/block = 4 waves x 4 CONCURRENT nodes each.
//   w_k from wcache (mode 1) or wmat (mode 0 fallback, no caching)
//   agg_j = sum_k w_jk * Hbuf[nbr_jk,:] / (sum_k w_jk + 1e-6)
//   o_j = leaky([x_j,agg_j].Ww + Wb);  OUT[n_j] = o_j/(||o_j||+1e-6)
//   FUSE: H1out[n_j] = leaky(OUT[n_j].Q1w + Q1b)   (Q1w L1-resident, shared)
// Batched GEMV: each sW read amortized over 4 nodes; broadcasts are b128.
// In-place safe (OUT may alias X): block reads only its own X rows, first.
// ---------------------------------------------------------------------------
template<bool FUSE>
__global__ __launch_bounds__(256) void k_conv(
    const float* __restrict__ X,
    const float* __restrict__ Hbuf,
    const float* __restrict__ Wmat,
    const float* __restrict__ wcache,
    const int*  __restrict__ nbr,
    const float* __restrict__ Ww,    // 128 x 64
    const float* __restrict__ Wb,
    const float* __restrict__ Q1w,   // 64 x 64 (FUSE)
    const float* __restrict__ Q1b,   // 64     (FUSE)
    float* __restrict__ OUT,
    float* __restrict__ H1out,
    int N, int mode)
{
    __shared__ float sW[128 * 64];   // 32 KB
    __shared__ float sx[4][4][64];   // 4 KB  [wid][j][c]
    __shared__ float sa[4][4][64];   // 4 KB
    __shared__ int   snb[4][128];    // 2 KB  [wid][j*32+k]
    __shared__ float ssw[4][128];    // 2 KB  => 44 KB, 3 blocks/CU

    const int tid  = threadIdx.x;
    const int wid  = tid >> 6;
    const int lane = tid & 63;
    const int bs   = blockIdx.x * 16;
    const int nbase = bs + wid * 4;

    // --- phase A: issue all irregular loads FIRST ---
    // wave-local entries: e in [0,128) = (j = e>>5, k = e&31)
    int gid[2]; float gw[2];
    #pragma unroll
    for (int u = 0; u < 2; ++u) {
        int e = u * 64 + lane;
        int n = nbase + (e >> 5); if (n >= N) n = N - 1;
        gid[u] = nbr[(size_t)n * KN + (e & 31)];
    }
    #pragma unroll
    for (int u = 0; u < 2; ++u) {
        int e = u * 64 + lane;
        int n = nbase + (e >> 5); if (n >= N) n = N - 1;
        gw[u] = (mode == 1) ? wcache[(size_t)n * KN + (e & 31)]
                            : Wmat[(size_t)n * (size_t)N + gid[u]];
    }
    float xr[4];
    #pragma unroll
    for (int j = 0; j < 4; ++j) {
        int n = nbase + j; if (n >= N) n = N - 1;
        xr[j] = X[(size_t)n * 64 + lane];
    }

    // --- stage Ww (float4, 8/thread) while loads are in flight ---
    {
        const float4* s = (const float4*)Ww; float4* d = (float4*)sW;
        #pragma unroll
        for (int i = 0; i < 8; ++i) d[i * 256 + tid] = s[i * 256 + tid];
    }
    // wave-local installs
    #pragma unroll
    for (int u = 0; u < 2; ++u) {
        int e = u * 64 + lane;
        snb[wid][e] = gid[u];
        ssw[wid][e] = gw[u];
    }
    #pragma unroll
    for (int j = 0; j < 4; ++j) sx[wid][j][lane] = xr[j];

    // --- sum of weights per node: 32-lane-half reductions on the regs ---
    float s0 = gw[0], s1 = gw[1];
    #pragma unroll
    for (int off = 16; off; off >>= 1) {
        s0 += __shfl_xor(s0, off);
        s1 += __shfl_xor(s1, off);
    }
    float sumw[4];
    sumw[0] = __shfl(s0, 0);  sumw[1] = __shfl(s0, 32);
    sumw[2] = __shfl(s1, 0);  sumw[3] = __shfl(s1, 32);

    // --- phase B: neighbor aggregation (ids/w from wave-local LDS, b128-able) ---
    #pragma unroll
    for (int j = 0; j < 4; ++j) {
        float agg = 0.f;
        #pragma unroll 8
        for (int k = 0; k < KN; ++k) {
            size_t id = (size_t)snb[wid][j * 32 + k];
            agg = fmaf(ssw[wid][j * 32 + k], Hbuf[id * 64 + lane], agg);
        }
        sa[wid][j][lane] = agg / (sumw[j] + 1e-6f);
    }
    __syncthreads();   // sW staged (sx/sa/snb/ssw all wave-local)

    // --- phase C: batched combine GEMV (4 nodes share every sW read) ---
    const float4* sx4 = (const float4*)&sx[wid][0][0];
    const float4* sa4 = (const float4*)&sa[wid][0][0];
    const float wb = Wb[lane];
    float acc[4] = {wb, wb, wb, wb};
    #pragma unroll
    for (int c4 = 0; c4 < 16; ++c4) {
        float4 xv[4];
        #pragma unroll
        for (int j = 0; j < 4; ++j) xv[j] = sx4[j * 16 + c4];
        #pragma unroll
        for (int u = 0; u < 4; ++u) {
            float wv = sW[(c4 * 4 + u) * 64 + lane];
            #pragma unroll
            for (int j = 0; j < 4; ++j)
                acc[j] = fmaf((&xv[j].x)[u], wv, acc[j]);
        }
    }
    #pragma unroll
    for (int c4 = 0; c4 < 16; ++c4) {
        float4 av[4];
        #pragma unroll
        for (int j = 0; j < 4; ++j) av[j] = sa4[j * 16 + c4];
        #pragma unroll
        for (int u = 0; u < 4; ++u) {
            float wv = sW[(64 + c4 * 4 + u) * 64 + lane];
            #pragma unroll
            for (int j = 0; j < 4; ++j)
                acc[j] = fmaf((&av[j].x)[u], wv, acc[j]);
        }
    }

    // --- phase D: leaky + L2 normalize + write ---
    float onorm[4];
    #pragma unroll
    for (int j = 0; j < 4; ++j) {
        float o = leaky_f(acc[j]);
        float ss = o * o;
        #pragma unroll
        for (int off = 32; off; off >>= 1) ss += __shfl_xor(ss, off);
        onorm[j] = o / (sqrtf(ss) + 1e-6f);
        int n = nbase + j;
        if (n < N) OUT[(size_t)n * 64 + lane] = onorm[j];
    }

    // --- phase E (FUSE): h1 = leaky(out0 . Q1 + b), batched, Q1w from L1 ---
    if (FUSE) {
        #pragma unroll
        for (int j = 0; j < 4; ++j) sx[wid][j][lane] = onorm[j];  // wave-local reuse
        const float qb = Q1b[lane];
        float acc1[4] = {qb, qb, qb, qb};
        #pragma unroll
        for (int c4 = 0; c4 < 16; ++c4) {
            float4 xv[4];
            #pragma unroll
            for (int j = 0; j < 4; ++j) xv[j] = sx4[j * 16 + c4];
            #pragma unroll
            for (int u = 0; u < 4; ++u) {
                float qv = Q1w[(c4 * 4 + u) * 64 + lane];  // shared by 4 nodes
                #pragma unroll
                for (int j = 0; j < 4; ++j)
                    acc1[j] = fmaf((&xv[j].x)[u], qv, acc1[j]);
            }
        }
        #pragma unroll
        for (int j = 0; j < 4; ++j) {
            int n = nbase + j;
            if (n < N) H1out[(size_t)n * 64 + lane] = leaky_f(acc1[j]);
        }
    }
}

extern "C" void kernel_launch(void* const* d_in, const int* in_sizes, int n_in,
                              void* d_out, int out_size, void* d_ws, size_t ws_size,
                              hipStream_t stream)
{
    const float* emb  = (const float*)d_in[0];  // (1, N, 64)
    const float* wmat = (const float*)d_in[1];  // (N, N)
    const int*   nbr  = (const int*)  d_in[2];  // (N, 32) int32
    const float* Q0w  = (const float*)d_in[3];
    const float* Q0b  = (const float*)d_in[4];
    const float* W0w  = (const float*)d_in[5];
    const float* W0b  = (const float*)d_in[6];
    const float* Q1w  = (const float*)d_in[7];
    const float* Q1b  = (const float*)d_in[8];
    const float* W1w  = (const float*)d_in[9];
    const float* W1b  = (const float*)d_in[10];
    float* out = (float*)d_out;

    const int N = in_sizes[2] / KN;             // 12000
    const size_t hbuf_bytes = (size_t)N * 64 * sizeof(float);
    const size_t wc_bytes   = (size_t)N * KN * sizeof(float);

    float* h0 = (float*)d_ws;
    float* h1 = (float*)((char*)d_ws + hbuf_bytes);
    bool use_wc = ws_size >= 2 * hbuf_bytes + wc_bytes;
    float* wcache = use_wc ? (float*)((char*)d_ws + 2 * hbuf_bytes) : nullptr;
    const int mode = use_wc ? 1 : 0;

    const int grid = (N + 15) / 16;    // 750

    // K_A: h0 + wcache (gather overlapped with batched dense GEMV)
    k_dense_gather<<<grid, 256, 0, stream>>>(emb, Q0w, Q0b, wmat, nbr,
                                             wcache, h0, N);
    // K_B: layer-0 conv (+ fused layer-1 dense): emb,h0 -> out0, h1
    k_conv<true><<<grid, 256, 0, stream>>>(emb, h0, wmat, wcache, nbr,
                                           W0w, W0b, Q1w, Q1b, out, h1, N, mode);
    // K_C: layer-1 conv (in-place on out)
    k_conv<false><<<grid, 256, 0, stream>>>(out, h1, wmat, wcache, nbr,
                                            W1w, W1b, nullptr, nullptr,
                                            out, nullptr, N, mode);
}

// Round 13
// 56.537 us; speedup vs baseline: 1.8628x; 1.8628x over previous
//
#include <hip/hip_runtime.h>
#include <math.h>

#define ALPHA 0.3f
#define KN 32

__device__ __forceinline__ float leaky_f(float x) { return x >= 0.f ? x : ALPHA * x; }

// lane-broadcast via v_readlane (VALU/SALU pipes -- NOT the DS unit)
__device__ __forceinline__ float rl(float x, int l) {
    return __int_as_float(__builtin_amdgcn_readlane(__float_as_int(x), l));
}
__device__ __forceinline__ int rli(int x, int l) {
    return __builtin_amdgcn_readlane(x, l);
}

// ---------------------------------------------------------------------------
// K_A: 16 nodes/block (4 waves x 4 nodes). ZERO LDS.
//   h0[n,h] = leaky( sum_c emb[n,c]*Q0w[c,h] + Q0b[h] )
//   wcache[n,k] = wmat[n, nbr[n,k]]   (issued FIRST; latency hides under GEMV)
// Q0 read from global (16KB, L1-hot, shared by all 4 nodes of the wave).
// ---------------------------------------------------------------------------
__global__ __launch_bounds__(256) void k_dense_gather(
    const float* __restrict__ X,
    const float* __restrict__ Qw,
    const float* __restrict__ Qb,
    const float* __restrict__ wmat,
    const int*  __restrict__ nbr,
    float* __restrict__ wcache,      // may be null
    float* __restrict__ Hout,
    int N)
{
    const int tid  = threadIdx.x;
    const int wid  = tid >> 6;
    const int lane = tid & 63;
    const int bs   = blockIdx.x * 16;
    const int nbase = bs + wid * 4;

    // --- random gathers first: 512 (node,k) entries = 2 per thread ---
    int gid[2]; float gw[2];
    #pragma unroll
    for (int u = 0; u < 2; ++u) {
        int e = tid + u * 256;
        int n = bs + (e >> 5); if (n >= N) n = N - 1;
        gid[u] = nbr[(size_t)n * KN + (e & 31)];
    }
    #pragma unroll
    for (int u = 0; u < 2; ++u) {
        int e = tid + u * 256;
        int n = bs + (e >> 5); if (n >= N) n = N - 1;
        gw[u] = wmat[(size_t)n * (size_t)N + gid[u]];
    }

    // --- own 4 x-rows into registers ---
    float xr0, xr1, xr2, xr3;
    {
        int n0 = nbase + 0; if (n0 >= N) n0 = N - 1;
        int n1 = nbase + 1; if (n1 >= N) n1 = N - 1;
        int n2 = nbase + 2; if (n2 >= N) n2 = N - 1;
        int n3 = nbase + 3; if (n3 >= N) n3 = N - 1;
        xr0 = X[(size_t)n0 * 64 + lane];
        xr1 = X[(size_t)n1 * 64 + lane];
        xr2 = X[(size_t)n2 * 64 + lane];
        xr3 = X[(size_t)n3 * 64 + lane];
    }

    // --- dense GEMV: Q row shared by 4 nodes; x broadcast via readlane ---
    const float qb = Qb[lane];
    float a0 = qb, a1 = qb, a2 = qb, a3 = qb;
    #pragma unroll
    for (int c = 0; c < 64; ++c) {
        float qv = Qw[c * 64 + lane];
        a0 = fmaf(rl(xr0, c), qv, a0);
        a1 = fmaf(rl(xr1, c), qv, a1);
        a2 = fmaf(rl(xr2, c), qv, a2);
        a3 = fmaf(rl(xr3, c), qv, a3);
    }
    if (nbase + 0 < N) Hout[(size_t)(nbase + 0) * 64 + lane] = leaky_f(a0);
    if (nbase + 1 < N) Hout[(size_t)(nbase + 1) * 64 + lane] = leaky_f(a1);
    if (nbase + 2 < N) Hout[(size_t)(nbase + 2) * 64 + lane] = leaky_f(a2);
    if (nbase + 3 < N) Hout[(size_t)(nbase + 3) * 64 + lane] = leaky_f(a3);

    // --- persist gathered weights (coalesced) ---
    if (wcache) {
        #pragma unroll
        for (int u = 0; u < 2; ++u) {
            int e = tid + u * 256;
            if (bs + (e >> 5) < N) wcache[(size_t)bs * KN + e] = gw[u];
        }
    }
}

// ---------------------------------------------------------------------------
// K_B/K_C: conv layer, 8 nodes/block = 4 waves x 1 node-pair. ZERO LDS.
//   lanes 0..31: node-a (id,w); lanes 32..63: node-b. Broadcasts via readlane.
//   W/Q1 read from global (L1/L2-hot), each load shared by the pair.
//   agg = sum_k w_k*Hbuf[nbr,:]/(sum_k w_k+1e-6)
//   o = leaky([x,agg].Ww + Wb); OUT = o/(||o||+1e-6)
//   FUSE: H1out = leaky(OUT.Q1w + Q1b)
// In-place safe (OUT may alias X): wave reads only its own 2 rows, first.
// ---------------------------------------------------------------------------
template<bool FUSE>
__global__ __launch_bounds__(256) void k_conv(
    const float* __restrict__ X,
    const float* __restrict__ Hbuf,
    const float* __restrict__ Wmat,
    const float* __restrict__ wcache,
    const int*  __restrict__ nbr,
    const float* __restrict__ Ww,    // 128 x 64
    const float* __restrict__ Wb,
    const float* __restrict__ Q1w,   // 64 x 64 (FUSE)
    const float* __restrict__ Q1b,   // 64     (FUSE)
    float* __restrict__ OUT,
    float* __restrict__ H1out,
    int N, int mode)
{
    const int tid  = threadIdx.x;
    const int wid  = tid >> 6;
    const int lane = tid & 63;
    const int bs   = blockIdx.x * 8;

    const int na = bs + wid * 2;
    const int nb = na + 1;
    const int ma = na < N ? na : N - 1;
    const int mb = nb < N ? nb : N - 1;

    // --- issue all irregular loads FIRST ---
    const int  myn = (lane < 32) ? ma : mb;
    const int  myk = lane & 31;
    const int  id  = nbr[(size_t)myn * KN + myk];
    const float w  = (mode == 1) ? wcache[(size_t)myn * KN + myk]
                                 : Wmat[(size_t)myn * (size_t)N + id];
    const float xa = X[(size_t)ma * 64 + lane];
    const float xb = X[(size_t)mb * 64 + lane];

    // --- sum of weights per node (32-lane-half butterfly) ---
    float s32 = w;
    #pragma unroll
    for (int off = 16; off; off >>= 1) s32 += __shfl_xor(s32, off);
    const float sumwa = rl(s32, 0);
    const float sumwb = rl(s32, 32);

    // --- neighbor aggregation: ids/weights broadcast via readlane ---
    float agga = 0.f, aggb = 0.f;
    #pragma unroll
    for (int k = 0; k < KN; ++k) {
        int   ia = rli(id, k);
        float wa = rl(w,  k);
        int   ib = rli(id, 32 + k);
        float wv = rl(w,  32 + k);
        agga = fmaf(wa, Hbuf[(size_t)ia * 64 + lane], agga);
        aggb = fmaf(wv, Hbuf[(size_t)ib * 64 + lane], aggb);
    }
    const float saa = agga / (sumwa + 1e-6f);
    const float sab = aggb / (sumwb + 1e-6f);

    // --- combine GEMV: W row (global, L1-hot) shared by the pair ---
    const float wb = Wb[lane];
    float acca = wb, accb = wb;
    #pragma unroll
    for (int c = 0; c < 64; ++c) {
        float wv = Ww[c * 64 + lane];
        acca = fmaf(rl(xa, c), wv, acca);
        accb = fmaf(rl(xb, c), wv, accb);
    }
    #pragma unroll
    for (int c = 0; c < 64; ++c) {
        float wv = Ww[(64 + c) * 64 + lane];
        acca = fmaf(rl(saa, c), wv, acca);
        accb = fmaf(rl(sab, c), wv, accb);
    }

    // --- leaky + L2 normalize ---
    float oa = leaky_f(acca), ob = leaky_f(accb);
    float ssa = oa * oa, ssb = ob * ob;
    #pragma unroll
    for (int off = 32; off; off >>= 1) {
        ssa += __shfl_xor(ssa, off);
        ssb += __shfl_xor(ssb, off);
    }
    const float ona = oa / (sqrtf(ssa) + 1e-6f);
    const float onb = ob / (sqrtf(ssb) + 1e-6f);
    if (na < N) OUT[(size_t)na * 64 + lane] = ona;
    if (nb < N) OUT[(size_t)nb * 64 + lane] = onb;

    // --- FUSE: h1 = leaky(out0 . Q1 + b); Q1 row shared by the pair ---
    if (FUSE) {
        float acc1a = Q1b[lane], acc1b = acc1a;
        #pragma unroll
        for (int c = 0; c < 64; ++c) {
            float qv = Q1w[c * 64 + lane];
            acc1a = fmaf(rl(ona, c), qv, acc1a);
            acc1b = fmaf(rl(onb, c), qv, acc1b);
        }
        if (na < N) H1out[(size_t)na * 64 + lane] = leaky_f(acc1a);
        if (nb < N) H1out[(size_t)nb * 64 + lane] = leaky_f(acc1b);
    }
}

extern "C" void kernel_launch(void* const* d_in, const int* in_sizes, int n_in,
                              void* d_out, int out_size, void* d_ws, size_t ws_size,
                              hipStream_t stream)
{
    const float* emb  = (const float*)d_in[0];  // (1, N, 64)
    const float* wmat = (const float*)d_in[1];  // (N, N)
    const int*   nbr  = (const int*)  d_in[2];  // (N, 32) int32
    const float* Q0w  = (const float*)d_in[3];
    const float* Q0b  = (const float*)d_in[4];
    const float* W0w  = (const float*)d_in[5];
    const float* W0b  = (const float*)d_in[6];
    const float* Q1w  = (const float*)d_in[7];
    const float* Q1b  = (const float*)d_in[8];
    const float* W1w  = (const float*)d_in[9];
    const float* W1b  = (const float*)d_in[10];
    float* out = (float*)d_out;

    const int N = in_sizes[2] / KN;             // 12000
    const size_t hbuf_bytes = (size_t)N * 64 * sizeof(float);
    const size_t wc_bytes   = (size_t)N * KN * sizeof(float);

    float* h0 = (float*)d_ws;
    float* h1 = (float*)((char*)d_ws + hbuf_bytes);
    bool use_wc = ws_size >= 2 * hbuf_bytes + wc_bytes;
    float* wcache = use_wc ? (float*)((char*)d_ws + 2 * hbuf_bytes) : nullptr;
    const int mode = use_wc ? 1 : 0;

    const int gridA = (N + 15) / 16;   // 750
    const int gridC = (N + 7) / 8;     // 1500

    // K_A: h0 + wcache (gather overlapped with DS-free dense GEMV)
    k_dense_gather<<<gridA, 256, 0, stream>>>(emb, Q0w, Q0b, wmat, nbr,
                                              wcache, h0, N);
    // K_B: layer-0 conv (+ fused layer-1 dense): emb,h0 -> out0, h1
    k_conv<true><<<gridC, 256, 0, stream>>>(emb, h0, wmat, wcache, nbr,
                                            W0w, W0b, Q1w, Q1b, out, h1, N, mode);
    // K_C: layer-1 conv (in-place on out)
    k_conv<false><<<gridC, 256, 0, stream>>>(out, h1, wmat, wcache, nbr,
                                             W1w, W1b, nullptr, nullptr,
                                             out, nullptr, N, mode);
}

// Round 14
// 54.347 us; speedup vs baseline: 1.9379x; 1.0403x over previous
//
#include <hip/hip_runtime.h>
#include <math.h>

#define ALPHA 0.3f
#define KN 32

__device__ __forceinline__ float leaky_f(float x) { return x >= 0.f ? x : ALPHA * x; }

// lane-broadcast via v_readlane (VALU pipe -- NOT the DS unit)
__device__ __forceinline__ float rl(float x, int l) {
    return __int_as_float(__builtin_amdgcn_readlane(__float_as_int(x), l));
}
__device__ __forceinline__ int rli(int x, int l) {
    return __builtin_amdgcn_readlane(x, l);
}

// ---------------------------------------------------------------------------
// K_A: 8 nodes/block (grid 1500 -> 2x in-flight random gathers vs 750):
//   h0[n,h] = leaky( sum_c emb[n,c]*Q0w[c,h] + Q0b[h] )   (2 nodes per wave)
//   wcache[n,k] = wmat[n, nbr[n,k]]   (1 entry/thread, issued FIRST)
// ZERO LDS.
// ---------------------------------------------------------------------------
__global__ __launch_bounds__(256) void k_dense_gather(
    const float* __restrict__ X,
    const float* __restrict__ Qw,
    const float* __restrict__ Qb,
    const float* __restrict__ wmat,
    const int*  __restrict__ nbr,
    float* __restrict__ wcache,      // may be null
    float* __restrict__ Hout,
    int N)
{
    const int tid  = threadIdx.x;
    const int wid  = tid >> 6;
    const int lane = tid & 63;
    const int bs   = blockIdx.x * 8;

    // --- random gather: 256 (node,k) entries = 1 per thread, issued first ---
    int gn = bs + (tid >> 5); if (gn >= N) gn = N - 1;
    const int   gid = nbr[(size_t)gn * KN + (tid & 31)];
    const float gw  = wmat[(size_t)gn * (size_t)N + gid];

    // --- own 2 x-rows ---
    const int n0 = bs + wid * 2;
    const int n1 = n0 + 1;
    const int m0 = n0 < N ? n0 : N - 1;
    const int m1 = n1 < N ? n1 : N - 1;
    const float x0 = X[(size_t)m0 * 64 + lane];
    const float x1 = X[(size_t)m1 * 64 + lane];

    // --- dense GEMV: Q row (L1-hot) shared by both nodes ---
    const float qb = Qb[lane];
    float a0 = qb, a1 = qb;
    #pragma unroll
    for (int c = 0; c < 64; ++c) {
        float qv = Qw[c * 64 + lane];
        a0 = fmaf(rl(x0, c), qv, a0);
        a1 = fmaf(rl(x1, c), qv, a1);
    }
    if (n0 < N) Hout[(size_t)n0 * 64 + lane] = leaky_f(a0);
    if (n1 < N) Hout[(size_t)n1 * 64 + lane] = leaky_f(a1);

    // --- persist gathered weights (coalesced, 1 float/thread) ---
    if (wcache && bs + (tid >> 5) < N)
        wcache[(size_t)bs * KN + tid] = gw;
}

// ---------------------------------------------------------------------------
// K_B/K_C: conv layer, 16 nodes/block = 4 waves x 4 CONCURRENT nodes (quad).
// ZERO LDS. Gather entries in 2 regs: u=0 -> nodes {0,1}, u=1 -> nodes {2,3};
// entry (j,k) lives at reg u=j>>1, src-lane (j&1)*32+k  (compile-time).
// Every W/Q row load (global, L1-hot) is shared by 4 nodes.
//   agg_j = sum_k w_jk*Hbuf[id_jk,:]/(sum_k w_jk+1e-6)
//   o_j = leaky([x_j,agg_j].Ww + Wb); OUT = o/(||o||+1e-6)
//   FUSE: H1out_j = leaky(OUT_j.Q1w + Q1b)
// In-place safe (OUT may alias X): block reads only its own X rows, first.
// ---------------------------------------------------------------------------
template<bool FUSE>
__global__ __launch_bounds__(256) void k_conv(
    const float* __restrict__ X,
    const float* __restrict__ Hbuf,
    const float* __restrict__ Wmat,
    const float* __restrict__ wcache,
    const int*  __restrict__ nbr,
    const float* __restrict__ Ww,    // 128 x 64
    const float* __restrict__ Wb,
    const float* __restrict__ Q1w,   // 64 x 64 (FUSE)
    const float* __restrict__ Q1b,   // 64     (FUSE)
    float* __restrict__ OUT,
    float* __restrict__ H1out,
    int N, int mode)
{
    const int tid  = threadIdx.x;
    const int wid  = tid >> 6;
    const int lane = tid & 63;
    const int bs   = blockIdx.x * 16;
    const int nbase = bs + wid * 4;

    // --- issue all irregular loads FIRST ---
    // reg u holds entries e = u*64+lane: node j = e>>5, k = e&31
    int   gid0, gid1; float gw0, gw1;
    {
        int e0 = lane,      n0 = nbase + (e0 >> 5);
        int e1 = 64 + lane, n1 = nbase + (e1 >> 5);
        if (n0 >= N) n0 = N - 1;
        if (n1 >= N) n1 = N - 1;
        gid0 = nbr[(size_t)n0 * KN + (e0 & 31)];
        gid1 = nbr[(size_t)n1 * KN + (e1 & 31)];
        if (mode == 1) {
            gw0 = wcache[(size_t)n0 * KN + (e0 & 31)];
            gw1 = wcache[(size_t)n1 * KN + (e1 & 31)];
        } else {
            gw0 = Wmat[(size_t)n0 * (size_t)N + gid0];
            gw1 = Wmat[(size_t)n1 * (size_t)N + gid1];
        }
    }
    // own 4 x-rows
    float xr0, xr1, xr2, xr3;
    {
        int p0 = nbase + 0; if (p0 >= N) p0 = N - 1;
        int p1 = nbase + 1; if (p1 >= N) p1 = N - 1;
        int p2 = nbase + 2; if (p2 >= N) p2 = N - 1;
        int p3 = nbase + 3; if (p3 >= N) p3 = N - 1;
        xr0 = X[(size_t)p0 * 64 + lane];
        xr1 = X[(size_t)p1 * 64 + lane];
        xr2 = X[(size_t)p2 * 64 + lane];
        xr3 = X[(size_t)p3 * 64 + lane];
    }

    // --- sum of weights per node (32-lane-half butterflies on both regs) ---
    float s0 = gw0, s1 = gw1;
    #pragma unroll
    for (int off = 16; off; off >>= 1) {
        s0 += __shfl_xor(s0, off);
        s1 += __shfl_xor(s1, off);
    }
    const float sumw0 = rl(s0, 0);
    const float sumw1 = rl(s0, 32);
    const float sumw2 = rl(s1, 0);
    const float sumw3 = rl(s1, 32);

    // --- neighbor aggregation: entry (j,k) via readlane (compile-time src) ---
    float ag0 = 0.f, ag1 = 0.f, ag2 = 0.f, ag3 = 0.f;
    #pragma unroll
    for (int k = 0; k < KN; ++k) {
        int   i0 = rli(gid0, k);        float w0 = rl(gw0, k);
        int   i1 = rli(gid0, 32 + k);   float w1 = rl(gw0, 32 + k);
        int   i2 = rli(gid1, k);        float w2 = rl(gw1, k);
        int   i3 = rli(gid1, 32 + k);   float w3 = rl(gw1, 32 + k);
        ag0 = fmaf(w0, Hbuf[(size_t)i0 * 64 + lane], ag0);
        ag1 = fmaf(w1, Hbuf[(size_t)i1 * 64 + lane], ag1);
        ag2 = fmaf(w2, Hbuf[(size_t)i2 * 64 + lane], ag2);
        ag3 = fmaf(w3, Hbuf[(size_t)i3 * 64 + lane], ag3);
    }
    const float sa0 = ag0 / (sumw0 + 1e-6f);
    const float sa1 = ag1 / (sumw1 + 1e-6f);
    const float sa2 = ag2 / (sumw2 + 1e-6f);
    const float sa3 = ag3 / (sumw3 + 1e-6f);

    // --- combine GEMV: each W row load shared by 4 nodes ---
    const float wb = Wb[lane];
    float ac0 = wb, ac1 = wb, ac2 = wb, ac3 = wb;
    #pragma unroll
    for (int c = 0; c < 64; ++c) {
        float wv = Ww[c * 64 + lane];
        ac0 = fmaf(rl(xr0, c), wv, ac0);
        ac1 = fmaf(rl(xr1, c), wv, ac1);
        ac2 = fmaf(rl(xr2, c), wv, ac2);
        ac3 = fmaf(rl(xr3, c), wv, ac3);
    }
    #pragma unroll
    for (int c = 0; c < 64; ++c) {
        float wv = Ww[(64 + c) * 64 + lane];
        ac0 = fmaf(rl(sa0, c), wv, ac0);
        ac1 = fmaf(rl(sa1, c), wv, ac1);
        ac2 = fmaf(rl(sa2, c), wv, ac2);
        ac3 = fmaf(rl(sa3, c), wv, ac3);
    }

    // --- leaky + L2 normalize + write ---
    float o0 = leaky_f(ac0), o1 = leaky_f(ac1);
    float o2 = leaky_f(ac2), o3 = leaky_f(ac3);
    float q0 = o0 * o0, q1 = o1 * o1, q2 = o2 * o2, q3 = o3 * o3;
    #pragma unroll
    for (int off = 32; off; off >>= 1) {
        q0 += __shfl_xor(q0, off);
        q1 += __shfl_xor(q1, off);
        q2 += __shfl_xor(q2, off);
        q3 += __shfl_xor(q3, off);
    }
    const float on0 = o0 / (sqrtf(q0) + 1e-6f);
    const float on1 = o1 / (sqrtf(q1) + 1e-6f);
    const float on2 = o2 / (sqrtf(q2) + 1e-6f);
    const float on3 = o3 / (sqrtf(q3) + 1e-6f);
    if (nbase + 0 < N) OUT[(size_t)(nbase + 0) * 64 + lane] = on0;
    if (nbase + 1 < N) OUT[(size_t)(nbase + 1) * 64 + lane] = on1;
    if (nbase + 2 < N) OUT[(size_t)(nbase + 2) * 64 + lane] = on2;
    if (nbase + 3 < N) OUT[(size_t)(nbase + 3) * 64 + lane] = on3;

    // --- FUSE: h1 = leaky(out0 . Q1 + b); Q row shared by 4 nodes ---
    if (FUSE) {
        const float qb = Q1b[lane];
        float b0 = qb, b1 = qb, b2 = qb, b3 = qb;
        #pragma unroll
        for (int c = 0; c < 64; ++c) {
            float qv = Q1w[c * 64 + lane];
            b0 = fmaf(rl(on0, c), qv, b0);
            b1 = fmaf(rl(on1, c), qv, b1);
            b2 = fmaf(rl(on2, c), qv, b2);
            b3 = fmaf(rl(on3, c), qv, b3);
        }
        if (nbase + 0 < N) H1out[(size_t)(nbase + 0) * 64 + lane] = leaky_f(b0);
        if (nbase + 1 < N) H1out[(size_t)(nbase + 1) * 64 + lane] = leaky_f(b1);
        if (nbase + 2 < N) H1out[(size_t)(nbase + 2) * 64 + lane] = leaky_f(b2);
        if (nbase + 3 < N) H1out[(size_t)(nbase + 3) * 64 + lane] = leaky_f(b3);
    }
}

extern "C" void kernel_launch(void* const* d_in, const int* in_sizes, int n_in,
                              void* d_out, int out_size, void* d_ws, size_t ws_size,
                              hipStream_t stream)
{
    const float* emb  = (const float*)d_in[0];  // (1, N, 64)
    const float* wmat = (const float*)d_in[1];  // (N, N)
    const int*   nbr  = (const int*)  d_in[2];  // (N, 32) int32
    const float* Q0w  = (const float*)d_in[3];
    const float* Q0b  = (const float*)d_in[4];
    const float* W0w  = (const float*)d_in[5];
    const float* W0b  = (const float*)d_in[6];
    const float* Q1w  = (const float*)d_in[7];
    const float* Q1b  = (const float*)d_in[8];
    const float* W1w  = (const float*)d_in[9];
    const float* W1b  = (const float*)d_in[10];
    float* out = (float*)d_out;

    const int N = in_sizes[2] / KN;             // 12000
    const size_t hbuf_bytes = (size_t)N * 64 * sizeof(float);
    const size_t wc_bytes   = (size_t)N * KN * sizeof(float);

    float* h0 = (float*)d_ws;
    float* h1 = (float*)((char*)d_ws + hbuf_bytes);
    bool use_wc = ws_size >= 2 * hbuf_bytes + wc_bytes;
    float* wcache = use_wc ? (float*)((char*)d_ws + 2 * hbuf_bytes) : nullptr;
    const int mode = use_wc ? 1 : 0;

    const int gridA = (N + 7) / 8;     // 1500: max in-flight random gathers
    const int gridC = (N + 15) / 16;   // 750: quad-sharing convs

    // K_A: h0 + wcache (gather overlapped with dense GEMV)
    k_dense_gather<<<gridA, 256, 0, stream>>>(emb, Q0w, Q0b, wmat, nbr,
                                              wcache, h0, N);
    // K_B: layer-0 conv (+ fused layer-1 dense): emb,h0 -> out0, h1
    k_conv<true><<<gridC, 256, 0, stream>>>(emb, h0, wmat, wcache, nbr,
                                            W0w, W0b, Q1w, Q1b, out, h1, N, mode);
    // K_C: layer-1 conv (in-place on out)
    k_conv<false><<<gridC, 256, 0, stream>>>(out, h1, wmat, wcache, nbr,
                                             W1w, W1b, nullptr, nullptr,
                                             out, nullptr, N, mode);
}